// Round 10
// baseline (371.258 us; speedup 1.0000x reference)
//
#include <hip/hip_runtime.h>
#include <hip/hip_bf16.h>

#define N_NODES 100000
#define N_EDGES 3200000
#define IN_CH 128
#define HID 64
#define N_CLASSES 10
#define NTILES 6250     // N_NODES / 16

// bucketized CSR build
#define NB 391          // ceil(100000/256) buckets of 256 nodes
#define NPB 256
#define BCAP 10240      // mean 8192, sigma~90
#define CHUNK 8192

typedef unsigned short u16;
typedef unsigned int u32;

typedef __attribute__((ext_vector_type(8))) short bf16x8;  // 8 bf16 = 4 VGPR
typedef __attribute__((ext_vector_type(4))) float f32x4;   // MFMA acc

static __device__ __forceinline__ float u2f(u32 u) {
    union { u32 i; float f; } v; v.i = u; return v.f;
}
static __device__ __forceinline__ u16 f2bf(float f) {
    __hip_bfloat16 b = __float2bfloat16(f);   // RNE
    return *(u16*)&b;
}

// ---------------- CSR build: pass A — bucket partition (packed u32 stage) ----------------

__global__ void __launch_bounds__(1024) passA_k(
        const int* __restrict__ src, const int* __restrict__ dst,
        int* __restrict__ bcnt, u32* __restrict__ stage) {
    __shared__ int lh[NB];
    __shared__ int lb[NB];
    for (int i = threadIdx.x; i < NB; i += 1024) lh[i] = 0;
    __syncthreads();
    int e0 = blockIdx.x * CHUNK;
#pragma unroll
    for (int k = 0; k < CHUNK / 1024; ++k) {
        int e = e0 + k * 1024 + threadIdx.x;
        if (e < N_EDGES) atomicAdd(&lh[dst[e] >> 8], 1);
    }
    __syncthreads();
    for (int i = threadIdx.x; i < NB; i += 1024) {
        lb[i] = atomicAdd(&bcnt[i], lh[i]);
        lh[i] = 0;
    }
    __syncthreads();
#pragma unroll
    for (int k = 0; k < CHUNK / 1024; ++k) {
        int e = e0 + k * 1024 + threadIdx.x;
        if (e < N_EDGES) {
            int d = dst[e];
            int b = d >> 8;
            int p = lb[b] + atomicAdd(&lh[b], 1);
            if (p < BCAP) stage[(size_t)b * BCAP + p] = ((u32)src[e] << 8) | (u32)(d & 255);
        }
    }
}

// ---------------- pass B — local bucket-scan + per-bucket CSR in LDS, coalesced out ------

__global__ void __launch_bounds__(1024) passB_k(
        const int* __restrict__ bcnt, const u32* __restrict__ stage,
        int* __restrict__ off, int* __restrict__ csr) {
    __shared__ int sc[512];
    __shared__ int ldeg[NPB];
    __shared__ int loff[NPB + 1];
    __shared__ int lcur[NPB];
    __shared__ int img[BCAP];
    int b = blockIdx.x;
    int tid = threadIdx.x;
    // local scan of bucket counts -> base
    if (tid < 512) sc[tid] = (tid < NB) ? min(bcnt[tid], BCAP) : 0;
    __syncthreads();
    for (int o = 1; o < 512; o <<= 1) {
        int t = (tid < 512 && tid >= o) ? sc[tid - o] : 0;
        __syncthreads();
        if (tid < 512) sc[tid] += t;
        __syncthreads();
    }
    int base = (b == 0) ? 0 : sc[b - 1];
    if (b == 0 && tid == 0) off[N_NODES] = sc[NB - 1];
    int nb = min(bcnt[b], BCAP);
    const u32* st = stage + (size_t)b * BCAP;
    if (tid < NPB) ldeg[tid] = 0;
    __syncthreads();
    for (int i = tid; i < nb; i += 1024) atomicAdd(&ldeg[st[i] & 255u], 1);
    __syncthreads();
    if (tid < NPB) lcur[tid] = ldeg[tid];
    __syncthreads();
    for (int o = 1; o < NPB; o <<= 1) {
        int t = (tid < NPB && tid >= o) ? lcur[tid - o] : 0;
        __syncthreads();
        if (tid < NPB) lcur[tid] += t;
        __syncthreads();
    }
    if (tid < NPB) loff[tid + 1] = lcur[tid];
    if (tid == 0) loff[0] = 0;
    __syncthreads();
    if (tid < NPB) {
        int gnode = (b << 8) + tid;
        if (gnode < N_NODES) off[gnode] = base + loff[tid];
        lcur[tid] = loff[tid];
    }
    __syncthreads();
    for (int i = tid; i < nb; i += 1024) {
        u32 pr = st[i];
        int p = atomicAdd(&lcur[pr & 255u], 1);
        img[p] = (int)(pr >> 8);
    }
    __syncthreads();
    for (int i = tid; i < nb; i += 1024) csr[base + i] = img[i];
}

// ---------------- MFMA helpers ----------------
// A-frag: lane holds A[lane&15][8*(lane>>4)+j]; B-frag: lane holds B[8*(lane>>4)+j][lane&15]
// D: lane reg i -> D[4*(lane>>4)+i][lane&15]   [verified m89 / round-9 refcheck]

static __device__ __forceinline__ bf16x8 bfragW(const float* __restrict__ W, int ncols,
                                                int kk, int nt, int lane) {
    int k0 = kk * 32 + ((lane >> 4) << 3);
    int col = nt * 16 + (lane & 15);
    bf16x8 b;
#pragma unroll
    for (int j = 0; j < 8; ++j) b[j] = (short)f2bf(W[(size_t)(k0 + j) * ncols + col]);
    return b;
}

static __device__ __forceinline__ bf16x8 bfragWl(const float* __restrict__ Wl,
                                                 int kk, int lane) {
    int k0 = kk * 32 + ((lane >> 4) << 3);
    int col = lane & 15;
    bf16x8 b;
#pragma unroll
    for (int j = 0; j < 8; ++j)
        b[j] = (col < N_CLASSES) ? (short)f2bf(Wl[(size_t)(k0 + j) * N_CLASSES + col]) : (short)0;
    return b;
}

// read A-frag from staged [16][68] u16 tile (b64-aligned reads)
static __device__ __forceinline__ bf16x8 afragSt(const u16* __restrict__ stw,
                                                 int kk, int lane) {
    const u16* p = stw + (size_t)(lane & 15) * 68 + kk * 32 + ((lane >> 4) << 3);
    uint2 q0 = *(const uint2*)p;
    uint2 q1 = *(const uint2*)(p + 4);
    union { uint2 u[2]; bf16x8 v; } cv;
    cv.u[0] = q0; cv.u[1] = q1;
    return cv.v;
}

// accumulate one bf16 16B chunk pair into f32[8] accumulators
#define ACC8(acc, c)                                                   \
    acc[0] += u2f(c.x << 16); acc[1] += u2f(c.x & 0xffff0000u);        \
    acc[2] += u2f(c.y << 16); acc[3] += u2f(c.y & 0xffff0000u);        \
    acc[4] += u2f(c.z << 16); acc[5] += u2f(c.z & 0xffff0000u);        \
    acc[6] += u2f(c.w << 16); acc[7] += u2f(c.w & 0xffff0000u);

// gather body: lane=(node lane&15, q=lane>>4); accA = ch[8q..8q+8), accB = ch[32+8q..+8)
#define GATHER16(TAB)                                                  \
    int node = n0 + (lane & 15);                                       \
    int q4 = (lane >> 4) << 4;                                         \
    const char* tb = (const char*)(TAB);                               \
    float accA[8], accB[8];                                            \
    {   const char* rp = tb + (size_t)node * 128 + q4;                 \
        uint4 c0 = *(const uint4*)rp;                                  \
        uint4 c1 = *(const uint4*)(rp + 64);                           \
        accA[0] = u2f(c0.x << 16); accA[1] = u2f(c0.x & 0xffff0000u);  \
        accA[2] = u2f(c0.y << 16); accA[3] = u2f(c0.y & 0xffff0000u);  \
        accA[4] = u2f(c0.z << 16); accA[5] = u2f(c0.z & 0xffff0000u);  \
        accA[6] = u2f(c0.w << 16); accA[7] = u2f(c0.w & 0xffff0000u);  \
        accB[0] = u2f(c1.x << 16); accB[1] = u2f(c1.x & 0xffff0000u);  \
        accB[2] = u2f(c1.y << 16); accB[3] = u2f(c1.y & 0xffff0000u);  \
        accB[4] = u2f(c1.z << 16); accB[5] = u2f(c1.z & 0xffff0000u);  \
        accB[6] = u2f(c1.w << 16); accB[7] = u2f(c1.w & 0xffff0000u); }\
    int e = off[node], e1 = off[node + 1];                             \
    while (__ballot(e < e1)) {                                         \
        if (e < e1) {                                                  \
            int s = csr[e];                                            \
            const char* rp = tb + (size_t)s * 128 + q4;                \
            uint4 c0 = *(const uint4*)rp;                              \
            uint4 c1 = *(const uint4*)(rp + 64);                       \
            ACC8(accA, c0) ACC8(accB, c1)                              \
        }                                                              \
        if (e + 1 < e1) {                                              \
            int s = csr[e + 1];                                        \
            const char* rp = tb + (size_t)s * 128 + q4;                \
            uint4 c0 = *(const uint4*)rp;                              \
            uint4 c1 = *(const uint4*)(rp + 64);                       \
            ACC8(accA, c0) ACC8(accB, c1)                              \
        }                                                              \
        e += 2;                                                        \
    }

// ---------------- y = x @ W1a (no bias), MFMA, stored bf16 ----------------

__global__ void __launch_bounds__(512) lin1_k(
        const float* __restrict__ x, const float* __restrict__ W1,
        u16* __restrict__ yb) {
    __shared__ u16 st[8][16][68];
    int wid = threadIdx.x >> 6, lane = threadIdx.x & 63;
    bf16x8 B[4][4];
#pragma unroll
    for (int kk = 0; kk < 4; ++kk)
#pragma unroll
        for (int nt = 0; nt < 4; ++nt) B[kk][nt] = bfragW(W1, 64, kk, nt, lane);
    int gw = blockIdx.x * 8 + wid;
    const int NW = 782 * 8;
    for (int t = gw; t < NTILES; t += NW) {
        int n0 = t << 4;
        f32x4 acc0 = {0.f, 0.f, 0.f, 0.f}, acc1 = acc0, acc2 = acc0, acc3 = acc0;
#pragma unroll
        for (int kk = 0; kk < 4; ++kk) {
            const float* xr = x + (size_t)(n0 + (lane & 15)) * IN_CH + kk * 32 + ((lane >> 4) << 3);
            float4 f0 = *(const float4*)xr;
            float4 f1 = *(const float4*)(xr + 4);
            bf16x8 a;
            a[0] = (short)f2bf(f0.x); a[1] = (short)f2bf(f0.y);
            a[2] = (short)f2bf(f0.z); a[3] = (short)f2bf(f0.w);
            a[4] = (short)f2bf(f1.x); a[5] = (short)f2bf(f1.y);
            a[6] = (short)f2bf(f1.z); a[7] = (short)f2bf(f1.w);
            acc0 = __builtin_amdgcn_mfma_f32_16x16x32_bf16(a, B[kk][0], acc0, 0, 0, 0);
            acc1 = __builtin_amdgcn_mfma_f32_16x16x32_bf16(a, B[kk][1], acc1, 0, 0, 0);
            acc2 = __builtin_amdgcn_mfma_f32_16x16x32_bf16(a, B[kk][2], acc2, 0, 0, 0);
            acc3 = __builtin_amdgcn_mfma_f32_16x16x32_bf16(a, B[kk][3], acc3, 0, 0, 0);
        }
        int r0 = (lane >> 4) << 2, cl = lane & 15;
#pragma unroll
        for (int i = 0; i < 4; ++i) {
            st[wid][r0 + i][cl]      = f2bf(acc0[i]);
            st[wid][r0 + i][16 + cl] = f2bf(acc1[i]);
            st[wid][r0 + i][32 + cl] = f2bf(acc2[i]);
            st[wid][r0 + i][48 + cl] = f2bf(acc3[i]);
        }
        __builtin_amdgcn_wave_barrier();
        {
            int row = lane >> 2, seg = lane & 3;
            const u16* sp = &st[wid][row][seg * 16];
            uint2 q0 = *(const uint2*)sp;
            uint2 q1 = *(const uint2*)(sp + 4);
            uint2 q2 = *(const uint2*)(sp + 8);
            uint2 q3 = *(const uint2*)(sp + 12);
            char* op = (char*)yb + (size_t)(n0 + row) * 128 + seg * 32;
            *(uint4*)op = make_uint4(q0.x, q0.y, q1.x, q1.y);
            *(uint4*)(op + 16) = make_uint4(q2.x, q2.y, q3.x, q3.y);
        }
        __builtin_amdgcn_wave_barrier();
    }
}

// ---------------- fused gather + layer-A MLP: h1 = relu(relu(agg(y)+b1a)@W2a+b2a) --------

__global__ void __launch_bounds__(512) gfA_k(
        const u16* __restrict__ yb, const int* __restrict__ off,
        const int* __restrict__ csr, const float* __restrict__ b1,
        const float* __restrict__ W2, const float* __restrict__ b2,
        u16* __restrict__ h1b) {
    __shared__ u16 sWf[8][64][8];     // W2a frags, block-shared (8 KB)
    __shared__ u16 st[8][16][68];     // per-wave output transpose tile
    int wid = threadIdx.x >> 6, lane = threadIdx.x & 63;
    for (int f = wid; f < 8; f += 8)
        *(bf16x8*)&sWf[f][lane][0] = bfragW(W2, 64, f >> 2, f & 3, lane);
    __syncthreads();
    int qq = (lane >> 4) << 3, cl = lane & 15;
    float b1A[8], b1B[8];
#pragma unroll
    for (int j = 0; j < 8; ++j) { b1A[j] = b1[qq + j]; b1B[j] = b1[32 + qq + j]; }
    float b2s[4];
#pragma unroll
    for (int nt = 0; nt < 4; ++nt) b2s[nt] = b2[nt * 16 + cl];
    int gw = blockIdx.x * 8 + wid;
    const int NW = 782 * 8;
    for (int t = gw; t < NTILES; t += NW) {
        int n0 = t << 4;
        GATHER16(yb)
        // A-frags directly from accumulators (+b1, relu)
        bf16x8 a0, a1;
#pragma unroll
        for (int j = 0; j < 8; ++j) {
            a0[j] = (short)f2bf(fmaxf(accA[j] + b1A[j], 0.f));
            a1[j] = (short)f2bf(fmaxf(accB[j] + b1B[j], 0.f));
        }
        f32x4 d0 = {0.f, 0.f, 0.f, 0.f}, d1 = d0, d2 = d0, d3 = d0;
        d0 = __builtin_amdgcn_mfma_f32_16x16x32_bf16(a0, *(const bf16x8*)&sWf[0][lane][0], d0, 0, 0, 0);
        d1 = __builtin_amdgcn_mfma_f32_16x16x32_bf16(a0, *(const bf16x8*)&sWf[1][lane][0], d1, 0, 0, 0);
        d2 = __builtin_amdgcn_mfma_f32_16x16x32_bf16(a0, *(const bf16x8*)&sWf[2][lane][0], d2, 0, 0, 0);
        d3 = __builtin_amdgcn_mfma_f32_16x16x32_bf16(a0, *(const bf16x8*)&sWf[3][lane][0], d3, 0, 0, 0);
        d0 = __builtin_amdgcn_mfma_f32_16x16x32_bf16(a1, *(const bf16x8*)&sWf[4][lane][0], d0, 0, 0, 0);
        d1 = __builtin_amdgcn_mfma_f32_16x16x32_bf16(a1, *(const bf16x8*)&sWf[5][lane][0], d1, 0, 0, 0);
        d2 = __builtin_amdgcn_mfma_f32_16x16x32_bf16(a1, *(const bf16x8*)&sWf[6][lane][0], d2, 0, 0, 0);
        d3 = __builtin_amdgcn_mfma_f32_16x16x32_bf16(a1, *(const bf16x8*)&sWf[7][lane][0], d3, 0, 0, 0);
        int r0 = (lane >> 4) << 2;
#pragma unroll
        for (int i = 0; i < 4; ++i) {
            st[wid][r0 + i][cl]      = f2bf(fmaxf(d0[i] + b2s[0], 0.f));
            st[wid][r0 + i][16 + cl] = f2bf(fmaxf(d1[i] + b2s[1], 0.f));
            st[wid][r0 + i][32 + cl] = f2bf(fmaxf(d2[i] + b2s[2], 0.f));
            st[wid][r0 + i][48 + cl] = f2bf(fmaxf(d3[i] + b2s[3], 0.f));
        }
        __builtin_amdgcn_wave_barrier();
        {
            int row = lane >> 2, seg = lane & 3;
            const u16* sp = &st[wid][row][seg * 16];
            uint2 w0 = *(const uint2*)sp;
            uint2 w1 = *(const uint2*)(sp + 4);
            uint2 w2 = *(const uint2*)(sp + 8);
            uint2 w3 = *(const uint2*)(sp + 12);
            char* op = (char*)h1b + (size_t)(n0 + row) * 128 + seg * 32;
            *(uint4*)op = make_uint4(w0.x, w0.y, w1.x, w1.y);
            *(uint4*)(op + 16) = make_uint4(w2.x, w2.y, w3.x, w3.y);
        }
        __builtin_amdgcn_wave_barrier();
    }
}

// ------- fused gather + layer-B MLP + classifier + log_softmax -> out ---------------------

__global__ void __launch_bounds__(512) gfB_k(
        const u16* __restrict__ h1b, const int* __restrict__ off,
        const int* __restrict__ csr, const float* __restrict__ W1,
        const float* __restrict__ b1, const float* __restrict__ W2,
        const float* __restrict__ b2, const float* __restrict__ Wl,
        const float* __restrict__ bl, float* __restrict__ out) {
    __shared__ u16 sWf[18][64][8];    // B1(0-7), B2(8-15), B3(16-17) — 18 KB
    __shared__ u16 st[8][16][68];
    int wid = threadIdx.x >> 6, lane = threadIdx.x & 63;
    for (int f = wid; f < 18; f += 8) {
        bf16x8 v;
        if (f < 8)       v = bfragW(W1, 64, f >> 2, f & 3, lane);
        else if (f < 16) v = bfragW(W2, 64, (f - 8) >> 2, (f - 8) & 3, lane);
        else             v = bfragWl(Wl, f - 16, lane);
        *(bf16x8*)&sWf[f][lane][0] = v;
    }
    __syncthreads();
    int cl = lane & 15;
    float b1s[4], b2s[4];
#pragma unroll
    for (int nt = 0; nt < 4; ++nt) { b1s[nt] = b1[nt * 16 + cl]; b2s[nt] = b2[nt * 16 + cl]; }
    float bls = (cl < N_CLASSES) ? bl[cl] : -1.0e30f;
    int gw = blockIdx.x * 8 + wid;
    const int NW = 782 * 8;
    for (int t = gw; t < NTILES; t += NW) {
        int n0 = t << 4;
        GATHER16(h1b)
        // GEMM1: u = relu(agg @ W1b + b1b); A-frags directly from accumulators
        bf16x8 a0, a1;
#pragma unroll
        for (int j = 0; j < 8; ++j) {
            a0[j] = (short)f2bf(accA[j]);
            a1[j] = (short)f2bf(accB[j]);
        }
        f32x4 u0 = {0.f, 0.f, 0.f, 0.f}, u1 = u0, u2 = u0, u3 = u0;
        u0 = __builtin_amdgcn_mfma_f32_16x16x32_bf16(a0, *(const bf16x8*)&sWf[0][lane][0], u0, 0, 0, 0);
        u1 = __builtin_amdgcn_mfma_f32_16x16x32_bf16(a0, *(const bf16x8*)&sWf[1][lane][0], u1, 0, 0, 0);
        u2 = __builtin_amdgcn_mfma_f32_16x16x32_bf16(a0, *(const bf16x8*)&sWf[2][lane][0], u2, 0, 0, 0);
        u3 = __builtin_amdgcn_mfma_f32_16x16x32_bf16(a0, *(const bf16x8*)&sWf[3][lane][0], u3, 0, 0, 0);
        u0 = __builtin_amdgcn_mfma_f32_16x16x32_bf16(a1, *(const bf16x8*)&sWf[4][lane][0], u0, 0, 0, 0);
        u1 = __builtin_amdgcn_mfma_f32_16x16x32_bf16(a1, *(const bf16x8*)&sWf[5][lane][0], u1, 0, 0, 0);
        u2 = __builtin_amdgcn_mfma_f32_16x16x32_bf16(a1, *(const bf16x8*)&sWf[6][lane][0], u2, 0, 0, 0);
        u3 = __builtin_amdgcn_mfma_f32_16x16x32_bf16(a1, *(const bf16x8*)&sWf[7][lane][0], u3, 0, 0, 0);
        int r0 = (lane >> 4) << 2;
#pragma unroll
        for (int i = 0; i < 4; ++i) {
            st[wid][r0 + i][cl]      = f2bf(fmaxf(u0[i] + b1s[0], 0.f));
            st[wid][r0 + i][16 + cl] = f2bf(fmaxf(u1[i] + b1s[1], 0.f));
            st[wid][r0 + i][32 + cl] = f2bf(fmaxf(u2[i] + b1s[2], 0.f));
            st[wid][r0 + i][48 + cl] = f2bf(fmaxf(u3[i] + b1s[3], 0.f));
        }
        __builtin_amdgcn_wave_barrier();
        // GEMM2: h2 = relu(u @ W2b + b2b)
        f32x4 d0 = {0.f, 0.f, 0.f, 0.f}, d1 = d0, d2 = d0, d3 = d0;
#pragma unroll
        for (int kk = 0; kk < 2; ++kk) {
            bf16x8 a = afragSt(&st[wid][0][0], kk, lane);
            d0 = __builtin_amdgcn_mfma_f32_16x16x32_bf16(a, *(const bf16x8*)&sWf[8 + kk * 4 + 0][lane][0], d0, 0, 0, 0);
            d1 = __builtin_amdgcn_mfma_f32_16x16x32_bf16(a, *(const bf16x8*)&sWf[8 + kk * 4 + 1][lane][0], d1, 0, 0, 0);
            d2 = __builtin_amdgcn_mfma_f32_16x16x32_bf16(a, *(const bf16x8*)&sWf[8 + kk * 4 + 2][lane][0], d2, 0, 0, 0);
            d3 = __builtin_amdgcn_mfma_f32_16x16x32_bf16(a, *(const bf16x8*)&sWf[8 + kk * 4 + 3][lane][0], d3, 0, 0, 0);
        }
        __builtin_amdgcn_wave_barrier();
#pragma unroll
        for (int i = 0; i < 4; ++i) {
            st[wid][r0 + i][cl]      = f2bf(fmaxf(d0[i] + b2s[0], 0.f));
            st[wid][r0 + i][16 + cl] = f2bf(fmaxf(d1[i] + b2s[1], 0.f));
            st[wid][r0 + i][32 + cl] = f2bf(fmaxf(d2[i] + b2s[2], 0.f));
            st[wid][r0 + i][48 + cl] = f2bf(fmaxf(d3[i] + b2s[3], 0.f));
        }
        __builtin_amdgcn_wave_barrier();
        // classifier + log-softmax
        f32x4 lg = {0.f, 0.f, 0.f, 0.f};
#pragma unroll
        for (int kk = 0; kk < 2; ++kk) {
            bf16x8 a = afragSt(&st[wid][0][0], kk, lane);
            lg = __builtin_amdgcn_mfma_f32_16x16x32_bf16(a, *(const bf16x8*)&sWf[16 + kk][lane][0], lg, 0, 0, 0);
        }
        __builtin_amdgcn_wave_barrier();
#pragma unroll
        for (int i = 0; i < 4; ++i) {
            float logit = lg[i] + bls;
            float m = logit;
            m = fmaxf(m, __shfl_xor(m, 1, 16));
            m = fmaxf(m, __shfl_xor(m, 2, 16));
            m = fmaxf(m, __shfl_xor(m, 4, 16));
            m = fmaxf(m, __shfl_xor(m, 8, 16));
            float ex = __expf(logit - m);
            float s = ex;
            s += __shfl_xor(s, 1, 16);
            s += __shfl_xor(s, 2, 16);
            s += __shfl_xor(s, 4, 16);
            s += __shfl_xor(s, 8, 16);
            float ls = __logf(s);
            if (cl < N_CLASSES)
                out[(size_t)(n0 + r0 + i) * N_CLASSES + cl] = logit - m - ls;
        }
    }
}

// ---------------- launch ----------------

extern "C" void kernel_launch(void* const* d_in, const int* in_sizes, int n_in,
                              void* d_out, int out_size, void* d_ws, size_t ws_size,
                              hipStream_t stream) {
    const float* x   = (const float*)d_in[0];
    const int*   ei  = (const int*)d_in[1];
    const int*   src = ei;
    const int*   dst = ei + N_EDGES;
    const float* W1a = (const float*)d_in[2];
    const float* b1a = (const float*)d_in[3];
    const float* W2a = (const float*)d_in[4];
    const float* b2a = (const float*)d_in[5];
    const float* W1b = (const float*)d_in[6];
    const float* b1b = (const float*)d_in[7];
    const float* W2b = (const float*)d_in[8];
    const float* b2b = (const float*)d_in[9];
    const float* Wl  = (const float*)d_in[10];
    const float* bl  = (const float*)d_in[11];
    float* out = (float*)d_out;

    char* ws = (char*)d_ws;
    size_t o = 0;
    auto alloc = [&](size_t bytes) -> void* {
        o = (o + 255) & ~(size_t)255;
        void* p = ws + o;
        o += bytes;
        return p;
    };
    int* bcnt  = (int*)alloc((size_t)NB * 4);
    int* off   = (int*)alloc((size_t)(N_NODES + 1) * 4);
    u32* stage = (u32*)alloc((size_t)NB * BCAP * 4);     // 16.0 MB (packed)
    int* csr   = (int*)alloc((size_t)N_EDGES * 4);       // 12.8 MB
    u16* yb    = (u16*)alloc((size_t)N_NODES * 64 * 2);  // 12.8 MB
    u16* h1b   = (u16*)alloc((size_t)N_NODES * 64 * 2);  // 12.8 MB

    hipMemsetAsync(bcnt, 0, (size_t)NB * 4, stream);

    const int nA = (N_EDGES + CHUNK - 1) / CHUNK;        // 391
    passA_k<<<nA, 1024, 0, stream>>>(src, dst, bcnt, stage);
    passB_k<<<NB, 1024, 0, stream>>>(bcnt, stage, off, csr);

    lin1_k<<<782, 512, 0, stream>>>(x, W1a, yb);
    gfA_k <<<782, 512, 0, stream>>>(yb, off, csr, b1a, W2a, b2a, h1b);
    gfB_k <<<782, 512, 0, stream>>>(h1b, off, csr, W1b, b1b, W2b, b2b, Wl, bl, out);
}